// Round 10
// baseline (259.188 us; speedup 1.0000x reference)
//
#include <hip/hip_runtime.h>
#include <math.h>

// Problem constants (fixed by setup_inputs)
#define NB 4
#define HID 128
#define TOTAL_PARAMS 8789
#define OFF_POSW 0       // 128*63
#define OFF_POSB 8064    // 128
#define OFF_SIGW 8192    // 128
#define OFF_SIGB 8320    // 1
#define OFF_COLW 8321    // 3*155
#define OFF_COLB 8786    // 3

// LDS layout (u32 units):
//  W-frags  [0, 8192):     ((n0*2+s)*2+p)*256 + l*4 + e2  (B-frags, hi/lo, both k-steps)
//  L2 wts   [8192, 8832):  h*5 + {posb, sigw, cw0, cw1, cw2}
//  samples  [8832, 10112): (wave*64+sample)*5 + {sig, c0, c1, c2, pad}   (round-7 layout)
#define WOFF  0
#define L2OFF 8192
#define SOFF  8832
#define LDSN  10112

typedef float        f32x4 __attribute__((ext_vector_type(4)));
typedef short        s16x8 __attribute__((ext_vector_type(8)));
typedef unsigned int u32x4 __attribute__((ext_vector_type(4)));

// Accurate sin/cos (Cody-Waite reduction), |arg| < ~2^14 rad.
__device__ __forceinline__ void sincos_acc(float arg, float& s, float& c) {
    const float INV_PI = 0.31830988618379067f;
    float nf = rintf(arg * INV_PI);
    float r = fmaf(nf, -3.140625f, arg);
    r = fmaf(nf, -9.675025940e-4f, r);
    r = fmaf(nf, -1.509957880e-7f, r);
    float ss = __sinf(r);
    float cc = __cosf(r);
    int n = (int)nf;
    if (n & 1) { ss = -ss; cc = -cc; }
    s = ss; c = cc;
}

__device__ __forceinline__ unsigned short bf16_rne(float x) {
    unsigned int u = __builtin_bit_cast(unsigned int, x);
    return (unsigned short)((u + 0x7FFFu + ((u >> 16) & 1u)) >> 16);
}
__device__ __forceinline__ float bf16_f(unsigned short h) {
    unsigned int u = ((unsigned int)h) << 16;
    return __builtin_bit_cast(float, u);
}
// split x into hi+lo bf16 (Markidis); pack pairs (x0,x1) into u32s (low = even elem)
__device__ __forceinline__ void split_pack(float x0, float x1, unsigned int& hi, unsigned int& lo) {
    unsigned short h0 = bf16_rne(x0), h1 = bf16_rne(x1);
    unsigned short l0 = bf16_rne(x0 - bf16_f(h0)), l1 = bf16_rne(x1 - bf16_f(h1));
    hi = (unsigned int)h0 | ((unsigned int)h1 << 16);
    lo = (unsigned int)l0 | ((unsigned int)l1 << 16);
}

// Identity posenc dim evaluator: d in [0,64).
// 0..2 = x,y,z; 3+6f+e: e<3 -> sin(2^f*pi*axis_e), e>=3 -> cos(2^f*pi*axis_{e-3}); 63 = pad 0.
__device__ __forceinline__ float pe_dim(int d, float qx, float qy, float qz) {
    if (d >= 63) return 0.0f;
    if (d < 3)  return (d == 0) ? qx : ((d == 1) ? qy : qz);
    int r  = d - 3;
    int f  = r / 6;
    int e  = r - f * 6;
    int is_cos = e >= 3;
    int ax = is_cos ? e - 3 : e;
    float q = (ax == 0) ? qx : ((ax == 1) ? qy : qz);
    float s, c;
    sincos_acc(ldexpf(q * 3.14159274101257324f, f), s, c);
    return is_cos ? c : s;
}

// Pre-kernel (identity map, byte-identical to the round-7-verified prep):
// pos_w -> MFMA B-fragments (hi/lo, both k-steps) once per batch, into d_ws.
__global__ void prep_wfrags_kernel(const float* __restrict__ params,
                                   unsigned int* __restrict__ ws)
{
    const int b = blockIdx.x;
    const float* __restrict__ pb = params + b * TOTAL_PARAMS;
    unsigned int* __restrict__ wsb = ws + b * 8192;
    const int tid = threadIdx.x;
    for (int it = 0; it < 16; ++it) {
        int idx = tid + it * 256;              // 4096 units: (n0,s,l,e2)
        int e2 = idx & 3;
        int l  = (idx >> 2) & 63;
        int s  = (idx >> 8) & 1;
        int n0 = idx >> 9;
        int k0 = s * 32 + ((l >> 4) << 3) + e2 * 2;
        int n  = n0 * 16 + (l & 15);
        float w0 = pb[OFF_POSW + n * 63 + k0];             // k0 <= 62 always
        float w1 = (k0 + 1 < 63) ? pb[OFF_POSW + n * 63 + k0 + 1] : 0.0f;
        unsigned int hi, lo;
        split_pack(w0, w1, hi, lo);
        int base = ((n0 * 2 + s) * 2) * 256 + l * 4 + e2;
        wsb[base]       = hi;
        wsb[base + 256] = lo;
    }
}

// ROUND-7 skeleton (256 threads, 4 waves, wave w = ray w, lane = sample) with:
//  (a) A-fragments built in registers per tile (content bit-identical to the
//      LDS-exchange version round 7 used), and
//  (b) tile-outer/n0-outer loop with fused layer-2 epilogue (per-accumulator
//      MFMA order and epilogue order bit-identical to round 7's phases).
// Stash formula / render phase are round-7 verbatim.
__attribute__((amdgpu_flat_work_group_size(256, 256), amdgpu_waves_per_eu(4, 4)))
__global__ void nerf_render_kernel(const float* __restrict__ params,
                                   const float* __restrict__ poses,
                                   const float* __restrict__ Ks,
                                   float* __restrict__ out,
                                   const unsigned int* __restrict__ ws,
                                   int use_ws)
{
    __shared__ unsigned int lds[LDSN];

    const int tid  = threadIdx.x;
    const int lane = tid & 63;                 // sample index along this wave's ray
    const int w    = tid >> 6;                 // wave id = ray-local id
    const int g    = lane >> 4;                // k-chunk group 0..3
    const int ray  = blockIdx.x * 4 + w;
    const int b    = ray >> 12;                // 4096 rays per batch
    const int p    = ray & 4095;
    const int i    = p >> 6;
    const int j    = p & 63;

    const float* __restrict__ pw = params + b * TOTAL_PARAMS;

    // ---- stage W B-fragments (identity map) ----
    if (use_ws) {
        const u32x4* __restrict__ wsrc = (const u32x4*)(ws + b * 8192);
        #pragma unroll
        for (int it = 0; it < 8; ++it) {
            int q = tid + it * 256;
            *(u32x4*)&lds[WOFF + q * 4] = wsrc[q];
        }
    } else {
        for (int it = 0; it < 16; ++it) {
            int idx = tid + it * 256;
            int e2 = idx & 3;
            int l  = (idx >> 2) & 63;
            int s  = (idx >> 8) & 1;
            int n0 = idx >> 9;
            int k0 = s * 32 + ((l >> 4) << 3) + e2 * 2;
            int n  = n0 * 16 + (l & 15);
            float w0 = pw[OFF_POSW + n * 63 + k0];
            float w1 = (k0 + 1 < 63) ? pw[OFF_POSW + n * 63 + k0 + 1] : 0.0f;
            unsigned int hi, lo;
            split_pack(w0, w1, hi, lo);
            int base = ((n0 * 2 + s) * 2) * 256 + l * 4 + e2;
            lds[WOFF + base]       = hi;
            lds[WOFF + base + 256] = lo;
        }
    }
    // ---- stage layer-2 weights [h][5] ----
    if (tid < HID) {
        lds[L2OFF + tid * 5 + 0] = __builtin_bit_cast(unsigned int, pw[OFF_POSB + tid]);
        lds[L2OFF + tid * 5 + 1] = __builtin_bit_cast(unsigned int, pw[OFF_SIGW + tid]);
        lds[L2OFF + tid * 5 + 2] = __builtin_bit_cast(unsigned int, pw[OFF_COLW + 0 * 155 + tid]);
        lds[L2OFF + tid * 5 + 3] = __builtin_bit_cast(unsigned int, pw[OFF_COLW + 1 * 155 + tid]);
        lds[L2OFF + tid * 5 + 4] = __builtin_bit_cast(unsigned int, pw[OFF_COLW + 2 * 155 + tid]);
    }

    // ---- ray setup (wave-uniform) ----
    const float* Kb = Ks + b * 9;
    float fx = Kb[0], cx = Kb[2], fy = Kb[4], cy = Kb[5];
    const float* Pb = poses + b * 16;
    float dcx = ((float)j - cx) / fx;
    float dcy = -(((float)i - cy) / fy);
    float dcz = -1.0f;
    float dx = Pb[0] * dcx + Pb[1] * dcy + Pb[2]  * dcz;
    float dy = Pb[4] * dcx + Pb[5] * dcy + Pb[6]  * dcz;
    float dz = Pb[8] * dcx + Pb[9] * dcy + Pb[10] * dcz;
    float ox = Pb[3], oy = Pb[7], oz = Pb[11];

    const float PI_F = 3.14159274101257324f;

    // ---- dir-encoding color contribution (per-ray, uniform weights) ----
    float dir0 = 0.0f, dir1 = 0.0f, dir2 = 0.0f;
    {
        const float* cw0 = pw + OFF_COLW + 0 * 155 + HID;
        const float* cw1 = pw + OFF_COLW + 1 * 155 + HID;
        const float* cw2 = pw + OFF_COLW + 2 * 155 + HID;
        dir0 += cw0[0] * dx + cw0[1] * dy + cw0[2] * dz;
        dir1 += cw1[0] * dx + cw1[1] * dy + cw1[2] * dz;
        dir2 += cw2[0] * dx + cw2[1] * dy + cw2[2] * dz;
        #pragma unroll
        for (int f = 0; f < 4; f++) {
            float freq = PI_F * (float)(1 << f);
            float sv[3], cv[3];
            sincos_acc(dx * freq, sv[0], cv[0]);
            sincos_acc(dy * freq, sv[1], cv[1]);
            sincos_acc(dz * freq, sv[2], cv[2]);
            #pragma unroll
            for (int d0 = 0; d0 < 3; d0++) {
                int ks = 3 + f * 6 + d0;
                int kc = ks + 3;
                dir0 = fmaf(cw0[ks], sv[d0], dir0);
                dir1 = fmaf(cw1[ks], sv[d0], dir1);
                dir2 = fmaf(cw2[ks], sv[d0], dir2);
                dir0 = fmaf(cw0[kc], cv[d0], dir0);
                dir1 = fmaf(cw1[kc], cv[d0], dir1);
                dir2 = fmaf(cw2[kc], cv[d0], dir2);
            }
        }
    }

    __syncthreads();   // W + L2w staged

    // ---- per-tile: build A in regs, 6 MFMA per n0, fused layer-2 epilogue ----
    #pragma unroll
    for (int mm = 0; mm < 4; ++mm) {
        // A-fragment for tile mm: slot (lane) holds row lane&15 (= sample
        // mm*16 + (lane&15)), dims k = s*32 + g*8 + e  (identity map).
        int smp_row = (mm << 4) + (lane & 15);
        float t  = (float)smp_row * (1.0f / 63.0f);
        float zz = 0.1f * (1.0f - t) + 10.0f * t;
        float qx = ox + dx * zz, qy = oy + dy * zz, qz = oz + dz * zz;
        s16x8 afh[2], afl[2];
        #pragma unroll
        for (int s = 0; s < 2; ++s) {
            int kb = s * 32 + g * 8;
            float v[8];
            #pragma unroll
            for (int e = 0; e < 8; ++e) v[e] = pe_dim(kb + e, qx, qy, qz);
            unsigned int h0, h1, h2, h3, l0, l1, l2, l3;
            split_pack(v[0], v[1], h0, l0);
            split_pack(v[2], v[3], h1, l1);
            split_pack(v[4], v[5], h2, l2);
            split_pack(v[6], v[7], h3, l3);
            afh[s] = __builtin_bit_cast(s16x8, (u32x4){h0, h1, h2, h3});
            afl[s] = __builtin_bit_cast(s16x8, (u32x4){l0, l1, l2, l3});
        }

        float sp[4], q0[4], q1[4], q2[4];
        #pragma unroll
        for (int r = 0; r < 4; ++r) { sp[r] = 0.0f; q0[r] = 0.0f; q1[r] = 0.0f; q2[r] = 0.0f; }

        #pragma unroll
        for (int n0 = 0; n0 < 8; ++n0) {
            s16x8 bh0 = *(const s16x8*)&lds[WOFF + ((n0 * 2 + 0) * 2 + 0) * 256 + lane * 4];
            s16x8 bl0 = *(const s16x8*)&lds[WOFF + ((n0 * 2 + 0) * 2 + 1) * 256 + lane * 4];
            s16x8 bh1 = *(const s16x8*)&lds[WOFF + ((n0 * 2 + 1) * 2 + 0) * 256 + lane * 4];
            s16x8 bl1 = *(const s16x8*)&lds[WOFF + ((n0 * 2 + 1) * 2 + 1) * 256 + lane * 4];
            f32x4 a = (f32x4){0.0f, 0.0f, 0.0f, 0.0f};
            // same per-accumulator order as round 7: s=0 {hh, hl, lh}, then s=1
            a = __builtin_amdgcn_mfma_f32_16x16x32_bf16(afh[0], bh0, a, 0, 0, 0);
            a = __builtin_amdgcn_mfma_f32_16x16x32_bf16(afh[0], bl0, a, 0, 0, 0);
            a = __builtin_amdgcn_mfma_f32_16x16x32_bf16(afl[0], bh0, a, 0, 0, 0);
            a = __builtin_amdgcn_mfma_f32_16x16x32_bf16(afh[1], bh1, a, 0, 0, 0);
            a = __builtin_amdgcn_mfma_f32_16x16x32_bf16(afh[1], bl1, a, 0, 0, 0);
            a = __builtin_amdgcn_mfma_f32_16x16x32_bf16(afl[1], bh1, a, 0, 0, 0);

            int h = n0 * 16 + (lane & 15);
            float pb_ = __builtin_bit_cast(float, lds[L2OFF + h * 5 + 0]);
            float sw_ = __builtin_bit_cast(float, lds[L2OFF + h * 5 + 1]);
            float c0_ = __builtin_bit_cast(float, lds[L2OFF + h * 5 + 2]);
            float c1_ = __builtin_bit_cast(float, lds[L2OFF + h * 5 + 3]);
            float c2_ = __builtin_bit_cast(float, lds[L2OFF + h * 5 + 4]);
            #pragma unroll
            for (int r = 0; r < 4; ++r) {
                float hv = fmaxf(a[r] + pb_, 0.0f);
                sp[r] = fmaf(sw_, hv, sp[r]);
                q0[r] = fmaf(c0_, hv, q0[r]);
                q1[r] = fmaf(c1_, hv, q1[r]);
                q2[r] = fmaf(c2_, hv, q2[r]);
            }
        }

        // reduce over the 16 h-columns (round-7 pattern)
        #pragma unroll
        for (int ofs = 1; ofs < 16; ofs <<= 1) {
            #pragma unroll
            for (int r = 0; r < 4; ++r) {
                sp[r] += __shfl_xor(sp[r], ofs);
                q0[r] += __shfl_xor(q0[r], ofs);
                q1[r] += __shfl_xor(q1[r], ofs);
                q2[r] += __shfl_xor(q2[r], ofs);
            }
        }

        // stash raw sums (round-7 verbatim formula; biases/dir added at render)
        if ((lane & 15) == 0) {
            #pragma unroll
            for (int r = 0; r < 4; ++r) {
                int sample = (mm << 4) | (g << 2) | r;
                int sb = SOFF + (w * 64 + sample) * 5;
                lds[sb + 0] = __builtin_bit_cast(unsigned int, sp[r]);
                lds[sb + 1] = __builtin_bit_cast(unsigned int, q0[r]);
                lds[sb + 2] = __builtin_bit_cast(unsigned int, q1[r]);
                lds[sb + 3] = __builtin_bit_cast(unsigned int, q2[r]);
            }
        }
    }

    __syncthreads();

    // ---- volume rendering (round-7 verbatim; lane = sample, wave = ray) ----
    int sb = SOFF + tid * 5;
    float sigma = __builtin_bit_cast(float, lds[sb + 0]) + pw[OFF_SIGB];
    float cc0   = __builtin_bit_cast(float, lds[sb + 1]) + pw[OFF_COLB + 0] + dir0;
    float cc1   = __builtin_bit_cast(float, lds[sb + 2]) + pw[OFF_COLB + 1] + dir1;
    float cc2   = __builtin_bit_cast(float, lds[sb + 3]) + pw[OFF_COLB + 2] + dir2;

    float t0 = (float)lane * (1.0f / 63.0f);
    float z  = 0.1f * (1.0f - t0) + 10.0f * t0;
    float t1 = (float)(lane + 1) * (1.0f / 63.0f);
    float z1 = 0.1f * (1.0f - t1) + 10.0f * t1;
    float dist = (lane == 63) ? 1e10f : (z1 - z);

    float alpha = 1.0f - expf(-fmaxf(sigma, 0.0f) * dist);
    float tr = 1.0f - alpha + 1e-10f;
    float prod = tr;
    #pragma unroll
    for (int off = 1; off < 64; off <<= 1) {
        float up = __shfl_up(prod, off);
        if (lane >= off) prod *= up;
    }
    float T = __shfl_up(prod, 1);
    if (lane == 0) T = 1.0f;
    float wgt = alpha * T;

    float r = 1.0f / (1.0f + expf(-cc0));
    float gcl = 1.0f / (1.0f + expf(-cc1));
    float bcl = 1.0f / (1.0f + expf(-cc2));

    float wr_ = wgt * r, wg_ = wgt * gcl, wb_ = wgt * bcl, wz_ = wgt * z, wa_ = wgt;
    #pragma unroll
    for (int off = 32; off >= 1; off >>= 1) {
        wr_ += __shfl_xor(wr_, off);
        wg_ += __shfl_xor(wg_, off);
        wb_ += __shfl_xor(wb_, off);
        wz_ += __shfl_xor(wz_, off);
        wa_ += __shfl_xor(wa_, off);
    }

    if (lane == 0) {
        float bg = 1.0f - wa_;
        out[(b * 3 + 0) * 4096 + p] = wr_ + bg;
        out[(b * 3 + 1) * 4096 + p] = wg_ + bg;
        out[(b * 3 + 2) * 4096 + p] = wb_ + bg;
        out[NB * 3 * 4096 + b * 4096 + p] = wz_;
        out[NB * 4 * 4096 + b * 4096 + p] = wa_;
    }
}

extern "C" void kernel_launch(void* const* d_in, const int* in_sizes, int n_in,
                              void* d_out, int out_size, void* d_ws, size_t ws_size,
                              hipStream_t stream) {
    const float* params = (const float*)d_in[0];
    const float* poses  = (const float*)d_in[1];
    const float* Ks     = (const float*)d_in[2];
    float* out = (float*)d_out;
    unsigned int* ws = (unsigned int*)d_ws;
    const int use_ws = (ws_size >= (size_t)(NB * 8192 * 4)) ? 1 : 0;
    if (use_ws) {
        prep_wfrags_kernel<<<dim3(NB), dim3(256), 0, stream>>>(params, ws);
    }
    // 4096 blocks x 256 threads: 4 rays/block, wave = ray (round-7 skeleton)
    nerf_render_kernel<<<dim3(4096), dim3(256), 0, stream>>>(params, poses, Ks, out, ws, use_ws);
}

// Round 11
// 200.725 us; speedup vs baseline: 1.2913x; 1.2913x over previous
//
#include <hip/hip_runtime.h>
#include <math.h>

// Problem constants (fixed by setup_inputs)
#define NB 4
#define HID 128
#define TOTAL_PARAMS 8789
#define OFF_POSW 0       // 128*63
#define OFF_POSB 8064    // 128
#define OFF_SIGW 8192    // 128
#define OFF_SIGB 8320    // 1
#define OFF_COLW 8321    // 3*155
#define OFF_COLB 8786    // 3

// LDS layout (u32 units):
//  W-frags  [0, 8192):     ((n0*2+s)*2+p)*256 + l*4 + e2  (B-frags, hi/lo, both k-steps)
//  L2 wts   [8192, 8832):  h*5 + {posb, sigw, cw0, cw1, cw2}
//  samples  [8832, 10112): (wave*64+sample)*5 + {sig, c0, c1, c2, pad}   (round-7 layout)
#define WOFF  0
#define L2OFF 8192
#define SOFF  8832
#define LDSN  10112

typedef float        f32x4 __attribute__((ext_vector_type(4)));
typedef short        s16x8 __attribute__((ext_vector_type(8)));
typedef unsigned int u32x4 __attribute__((ext_vector_type(4)));

// Accurate sin/cos (Cody-Waite reduction), |arg| < ~2^14 rad.
__device__ __forceinline__ void sincos_acc(float arg, float& s, float& c) {
    const float INV_PI = 0.31830988618379067f;
    float nf = rintf(arg * INV_PI);
    float r = fmaf(nf, -3.140625f, arg);
    r = fmaf(nf, -9.675025940e-4f, r);
    r = fmaf(nf, -1.509957880e-7f, r);
    float ss = __sinf(r);
    float cc = __cosf(r);
    int n = (int)nf;
    if (n & 1) { ss = -ss; cc = -cc; }
    s = ss; c = cc;
}

__device__ __forceinline__ unsigned short bf16_rne(float x) {
    unsigned int u = __builtin_bit_cast(unsigned int, x);
    return (unsigned short)((u + 0x7FFFu + ((u >> 16) & 1u)) >> 16);
}
__device__ __forceinline__ float bf16_f(unsigned short h) {
    unsigned int u = ((unsigned int)h) << 16;
    return __builtin_bit_cast(float, u);
}
// split x into hi+lo bf16 (Markidis); pack pairs (x0,x1) into u32s (low = even elem)
__device__ __forceinline__ void split_pack(float x0, float x1, unsigned int& hi, unsigned int& lo) {
    unsigned short h0 = bf16_rne(x0), h1 = bf16_rne(x1);
    unsigned short l0 = bf16_rne(x0 - bf16_f(h0)), l1 = bf16_rne(x1 - bf16_f(h1));
    hi = (unsigned int)h0 | ((unsigned int)h1 << 16);
    lo = (unsigned int)l0 | ((unsigned int)l1 << 16);
}

// Identity posenc dim evaluator: d in [0,64).
// 0..2 = x,y,z; 3+6f+e: e<3 -> sin(2^f*pi*axis_e), e>=3 -> cos(2^f*pi*axis_{e-3}); 63 = pad 0.
__device__ __forceinline__ float pe_dim(int d, float qx, float qy, float qz) {
    if (d >= 63) return 0.0f;
    if (d < 3)  return (d == 0) ? qx : ((d == 1) ? qy : qz);
    int r  = d - 3;
    int f  = r / 6;
    int e  = r - f * 6;
    int is_cos = e >= 3;
    int ax = is_cos ? e - 3 : e;
    float q = (ax == 0) ? qx : ((ax == 1) ? qy : qz);
    float s, c;
    sincos_acc(ldexpf(q * 3.14159274101257324f, f), s, c);
    return is_cos ? c : s;
}

// Pre-kernel (identity map, byte-identical to the round-7-verified prep):
// pos_w -> MFMA B-fragments (hi/lo, both k-steps) once per batch, into d_ws.
__global__ void prep_wfrags_kernel(const float* __restrict__ params,
                                   unsigned int* __restrict__ ws)
{
    const int b = blockIdx.x;
    const float* __restrict__ pb = params + b * TOTAL_PARAMS;
    unsigned int* __restrict__ wsb = ws + b * 8192;
    const int tid = threadIdx.x;
    for (int it = 0; it < 16; ++it) {
        int idx = tid + it * 256;              // 4096 units: (n0,s,l,e2)
        int e2 = idx & 3;
        int l  = (idx >> 2) & 63;
        int s  = (idx >> 8) & 1;
        int n0 = idx >> 9;
        int k0 = s * 32 + ((l >> 4) << 3) + e2 * 2;
        int n  = n0 * 16 + (l & 15);
        float w0 = pb[OFF_POSW + n * 63 + k0];             // k0 <= 62 always
        float w1 = (k0 + 1 < 63) ? pb[OFF_POSW + n * 63 + k0 + 1] : 0.0f;
        unsigned int hi, lo;
        split_pack(w0, w1, hi, lo);
        int base = ((n0 * 2 + s) * 2) * 256 + l * 4 + e2;
        wsb[base]       = hi;
        wsb[base + 256] = lo;
    }
}

// ROUND-10 kernel (verified: absmax 0.015625) with ONE change: the mm loop is
// NOT unrolled (#pragma unroll 1). Round-10's full mm x n0 unroll (32 iters)
// hoisted ~128 ds_read dests -> live set >> 128-reg budget -> 379 MB scratch
// WRITE + 198 MB FETCH. Per-mm live set (~90 regs) fits 4-waves/EU budget.
__attribute__((amdgpu_flat_work_group_size(256, 256), amdgpu_waves_per_eu(4, 4)))
__global__ void nerf_render_kernel(const float* __restrict__ params,
                                   const float* __restrict__ poses,
                                   const float* __restrict__ Ks,
                                   float* __restrict__ out,
                                   const unsigned int* __restrict__ ws,
                                   int use_ws)
{
    __shared__ unsigned int lds[LDSN];

    const int tid  = threadIdx.x;
    const int lane = tid & 63;                 // sample index along this wave's ray
    const int w    = tid >> 6;                 // wave id = ray-local id
    const int g    = lane >> 4;                // k-chunk group 0..3
    const int ray  = blockIdx.x * 4 + w;
    const int b    = ray >> 12;                // 4096 rays per batch
    const int p    = ray & 4095;
    const int i    = p >> 6;
    const int j    = p & 63;

    const float* __restrict__ pw = params + b * TOTAL_PARAMS;

    // ---- stage W B-fragments (identity map) ----
    if (use_ws) {
        const u32x4* __restrict__ wsrc = (const u32x4*)(ws + b * 8192);
        #pragma unroll
        for (int it = 0; it < 8; ++it) {
            int q = tid + it * 256;
            *(u32x4*)&lds[WOFF + q * 4] = wsrc[q];
        }
    } else {
        for (int it = 0; it < 16; ++it) {
            int idx = tid + it * 256;
            int e2 = idx & 3;
            int l  = (idx >> 2) & 63;
            int s  = (idx >> 8) & 1;
            int n0 = idx >> 9;
            int k0 = s * 32 + ((l >> 4) << 3) + e2 * 2;
            int n  = n0 * 16 + (l & 15);
            float w0 = pw[OFF_POSW + n * 63 + k0];
            float w1 = (k0 + 1 < 63) ? pw[OFF_POSW + n * 63 + k0 + 1] : 0.0f;
            unsigned int hi, lo;
            split_pack(w0, w1, hi, lo);
            int base = ((n0 * 2 + s) * 2) * 256 + l * 4 + e2;
            lds[WOFF + base]       = hi;
            lds[WOFF + base + 256] = lo;
        }
    }
    // ---- stage layer-2 weights [h][5] ----
    if (tid < HID) {
        lds[L2OFF + tid * 5 + 0] = __builtin_bit_cast(unsigned int, pw[OFF_POSB + tid]);
        lds[L2OFF + tid * 5 + 1] = __builtin_bit_cast(unsigned int, pw[OFF_SIGW + tid]);
        lds[L2OFF + tid * 5 + 2] = __builtin_bit_cast(unsigned int, pw[OFF_COLW + 0 * 155 + tid]);
        lds[L2OFF + tid * 5 + 3] = __builtin_bit_cast(unsigned int, pw[OFF_COLW + 1 * 155 + tid]);
        lds[L2OFF + tid * 5 + 4] = __builtin_bit_cast(unsigned int, pw[OFF_COLW + 2 * 155 + tid]);
    }

    // ---- ray setup (wave-uniform) ----
    const float* Kb = Ks + b * 9;
    float fx = Kb[0], cx = Kb[2], fy = Kb[4], cy = Kb[5];
    const float* Pb = poses + b * 16;
    float dcx = ((float)j - cx) / fx;
    float dcy = -(((float)i - cy) / fy);
    float dcz = -1.0f;
    float dx = Pb[0] * dcx + Pb[1] * dcy + Pb[2]  * dcz;
    float dy = Pb[4] * dcx + Pb[5] * dcy + Pb[6]  * dcz;
    float dz = Pb[8] * dcx + Pb[9] * dcy + Pb[10] * dcz;
    float ox = Pb[3], oy = Pb[7], oz = Pb[11];

    const float PI_F = 3.14159274101257324f;

    // ---- dir-encoding color contribution (per-ray, uniform weights) ----
    float dir0 = 0.0f, dir1 = 0.0f, dir2 = 0.0f;
    {
        const float* cw0 = pw + OFF_COLW + 0 * 155 + HID;
        const float* cw1 = pw + OFF_COLW + 1 * 155 + HID;
        const float* cw2 = pw + OFF_COLW + 2 * 155 + HID;
        dir0 += cw0[0] * dx + cw0[1] * dy + cw0[2] * dz;
        dir1 += cw1[0] * dx + cw1[1] * dy + cw1[2] * dz;
        dir2 += cw2[0] * dx + cw2[1] * dy + cw2[2] * dz;
        #pragma unroll
        for (int f = 0; f < 4; f++) {
            float freq = PI_F * (float)(1 << f);
            float sv[3], cv[3];
            sincos_acc(dx * freq, sv[0], cv[0]);
            sincos_acc(dy * freq, sv[1], cv[1]);
            sincos_acc(dz * freq, sv[2], cv[2]);
            #pragma unroll
            for (int d0 = 0; d0 < 3; d0++) {
                int ks = 3 + f * 6 + d0;
                int kc = ks + 3;
                dir0 = fmaf(cw0[ks], sv[d0], dir0);
                dir1 = fmaf(cw1[ks], sv[d0], dir1);
                dir2 = fmaf(cw2[ks], sv[d0], dir2);
                dir0 = fmaf(cw0[kc], cv[d0], dir0);
                dir1 = fmaf(cw1[kc], cv[d0], dir1);
                dir2 = fmaf(cw2[kc], cv[d0], dir2);
            }
        }
    }

    __syncthreads();   // W + L2w staged

    // ---- per-tile: build A in regs, 6 MFMA per n0, fused layer-2 epilogue ----
    #pragma unroll 1
    for (int mm = 0; mm < 4; ++mm) {
        // A-fragment for tile mm: slot (lane) holds row lane&15 (= sample
        // mm*16 + (lane&15)), dims k = s*32 + g*8 + e  (identity map).
        int smp_row = (mm << 4) + (lane & 15);
        float t  = (float)smp_row * (1.0f / 63.0f);
        float zz = 0.1f * (1.0f - t) + 10.0f * t;
        float qx = ox + dx * zz, qy = oy + dy * zz, qz = oz + dz * zz;
        s16x8 afh[2], afl[2];
        #pragma unroll
        for (int s = 0; s < 2; ++s) {
            int kb = s * 32 + g * 8;
            float v[8];
            #pragma unroll
            for (int e = 0; e < 8; ++e) v[e] = pe_dim(kb + e, qx, qy, qz);
            unsigned int h0, h1, h2, h3, l0, l1, l2, l3;
            split_pack(v[0], v[1], h0, l0);
            split_pack(v[2], v[3], h1, l1);
            split_pack(v[4], v[5], h2, l2);
            split_pack(v[6], v[7], h3, l3);
            afh[s] = __builtin_bit_cast(s16x8, (u32x4){h0, h1, h2, h3});
            afl[s] = __builtin_bit_cast(s16x8, (u32x4){l0, l1, l2, l3});
        }

        float sp[4], q0[4], q1[4], q2[4];
        #pragma unroll
        for (int r = 0; r < 4; ++r) { sp[r] = 0.0f; q0[r] = 0.0f; q1[r] = 0.0f; q2[r] = 0.0f; }

        #pragma unroll
        for (int n0 = 0; n0 < 8; ++n0) {
            s16x8 bh0 = *(const s16x8*)&lds[WOFF + ((n0 * 2 + 0) * 2 + 0) * 256 + lane * 4];
            s16x8 bl0 = *(const s16x8*)&lds[WOFF + ((n0 * 2 + 0) * 2 + 1) * 256 + lane * 4];
            s16x8 bh1 = *(const s16x8*)&lds[WOFF + ((n0 * 2 + 1) * 2 + 0) * 256 + lane * 4];
            s16x8 bl1 = *(const s16x8*)&lds[WOFF + ((n0 * 2 + 1) * 2 + 1) * 256 + lane * 4];
            f32x4 a = (f32x4){0.0f, 0.0f, 0.0f, 0.0f};
            // same per-accumulator order as round 7: s=0 {hh, hl, lh}, then s=1
            a = __builtin_amdgcn_mfma_f32_16x16x32_bf16(afh[0], bh0, a, 0, 0, 0);
            a = __builtin_amdgcn_mfma_f32_16x16x32_bf16(afh[0], bl0, a, 0, 0, 0);
            a = __builtin_amdgcn_mfma_f32_16x16x32_bf16(afl[0], bh0, a, 0, 0, 0);
            a = __builtin_amdgcn_mfma_f32_16x16x32_bf16(afh[1], bh1, a, 0, 0, 0);
            a = __builtin_amdgcn_mfma_f32_16x16x32_bf16(afh[1], bl1, a, 0, 0, 0);
            a = __builtin_amdgcn_mfma_f32_16x16x32_bf16(afl[1], bh1, a, 0, 0, 0);

            int h = n0 * 16 + (lane & 15);
            float pb_ = __builtin_bit_cast(float, lds[L2OFF + h * 5 + 0]);
            float sw_ = __builtin_bit_cast(float, lds[L2OFF + h * 5 + 1]);
            float c0_ = __builtin_bit_cast(float, lds[L2OFF + h * 5 + 2]);
            float c1_ = __builtin_bit_cast(float, lds[L2OFF + h * 5 + 3]);
            float c2_ = __builtin_bit_cast(float, lds[L2OFF + h * 5 + 4]);
            #pragma unroll
            for (int r = 0; r < 4; ++r) {
                float hv = fmaxf(a[r] + pb_, 0.0f);
                sp[r] = fmaf(sw_, hv, sp[r]);
                q0[r] = fmaf(c0_, hv, q0[r]);
                q1[r] = fmaf(c1_, hv, q1[r]);
                q2[r] = fmaf(c2_, hv, q2[r]);
            }
        }

        // reduce over the 16 h-columns (round-7 pattern)
        #pragma unroll
        for (int ofs = 1; ofs < 16; ofs <<= 1) {
            #pragma unroll
            for (int r = 0; r < 4; ++r) {
                sp[r] += __shfl_xor(sp[r], ofs);
                q0[r] += __shfl_xor(q0[r], ofs);
                q1[r] += __shfl_xor(q1[r], ofs);
                q2[r] += __shfl_xor(q2[r], ofs);
            }
        }

        // stash raw sums (round-7 verbatim formula; biases/dir added at render)
        if ((lane & 15) == 0) {
            #pragma unroll
            for (int r = 0; r < 4; ++r) {
                int sample = (mm << 4) | (g << 2) | r;
                int sb = SOFF + (w * 64 + sample) * 5;
                lds[sb + 0] = __builtin_bit_cast(unsigned int, sp[r]);
                lds[sb + 1] = __builtin_bit_cast(unsigned int, q0[r]);
                lds[sb + 2] = __builtin_bit_cast(unsigned int, q1[r]);
                lds[sb + 3] = __builtin_bit_cast(unsigned int, q2[r]);
            }
        }
    }

    __syncthreads();

    // ---- volume rendering (round-7 verbatim; lane = sample, wave = ray) ----
    int sb = SOFF + tid * 5;
    float sigma = __builtin_bit_cast(float, lds[sb + 0]) + pw[OFF_SIGB];
    float cc0   = __builtin_bit_cast(float, lds[sb + 1]) + pw[OFF_COLB + 0] + dir0;
    float cc1   = __builtin_bit_cast(float, lds[sb + 2]) + pw[OFF_COLB + 1] + dir1;
    float cc2   = __builtin_bit_cast(float, lds[sb + 3]) + pw[OFF_COLB + 2] + dir2;

    float t0 = (float)lane * (1.0f / 63.0f);
    float z  = 0.1f * (1.0f - t0) + 10.0f * t0;
    float t1 = (float)(lane + 1) * (1.0f / 63.0f);
    float z1 = 0.1f * (1.0f - t1) + 10.0f * t1;
    float dist = (lane == 63) ? 1e10f : (z1 - z);

    float alpha = 1.0f - expf(-fmaxf(sigma, 0.0f) * dist);
    float tr = 1.0f - alpha + 1e-10f;
    float prod = tr;
    #pragma unroll
    for (int off = 1; off < 64; off <<= 1) {
        float up = __shfl_up(prod, off);
        if (lane >= off) prod *= up;
    }
    float T = __shfl_up(prod, 1);
    if (lane == 0) T = 1.0f;
    float wgt = alpha * T;

    float r = 1.0f / (1.0f + expf(-cc0));
    float gcl = 1.0f / (1.0f + expf(-cc1));
    float bcl = 1.0f / (1.0f + expf(-cc2));

    float wr_ = wgt * r, wg_ = wgt * gcl, wb_ = wgt * bcl, wz_ = wgt * z, wa_ = wgt;
    #pragma unroll
    for (int off = 32; off >= 1; off >>= 1) {
        wr_ += __shfl_xor(wr_, off);
        wg_ += __shfl_xor(wg_, off);
        wb_ += __shfl_xor(wb_, off);
        wz_ += __shfl_xor(wz_, off);
        wa_ += __shfl_xor(wa_, off);
    }

    if (lane == 0) {
        float bg = 1.0f - wa_;
        out[(b * 3 + 0) * 4096 + p] = wr_ + bg;
        out[(b * 3 + 1) * 4096 + p] = wg_ + bg;
        out[(b * 3 + 2) * 4096 + p] = wb_ + bg;
        out[NB * 3 * 4096 + b * 4096 + p] = wz_;
        out[NB * 4 * 4096 + b * 4096 + p] = wa_;
    }
}

extern "C" void kernel_launch(void* const* d_in, const int* in_sizes, int n_in,
                              void* d_out, int out_size, void* d_ws, size_t ws_size,
                              hipStream_t stream) {
    const float* params = (const float*)d_in[0];
    const float* poses  = (const float*)d_in[1];
    const float* Ks     = (const float*)d_in[2];
    float* out = (float*)d_out;
    unsigned int* ws = (unsigned int*)d_ws;
    const int use_ws = (ws_size >= (size_t)(NB * 8192 * 4)) ? 1 : 0;
    if (use_ws) {
        prep_wfrags_kernel<<<dim3(NB), dim3(256), 0, stream>>>(params, ws);
    }
    // 4096 blocks x 256 threads: 4 rays/block, wave = ray (round-7 skeleton)
    nerf_render_kernel<<<dim3(4096), dim3(256), 0, stream>>>(params, poses, Ks, out, ws, use_ws);
}